// Round 1
// baseline (6264.789 us; speedup 1.0000x reference)
//
#include <hip/hip_runtime.h>
#include <hip/hip_bf16.h>

#define T_LEN 512
#define BATCH 8
#define HID   256
#define G4    1024   // 4H
#define EMBD  64
#define VOC   32000
#define KDIM  512    // 2H

typedef __attribute__((ext_vector_type(8))) short bh8;    // 8 bf16 (4 VGPRs)
typedef __attribute__((ext_vector_type(4))) short s4v;    // 4 bf16 (8 B)
typedef __attribute__((ext_vector_type(4))) float fx4;    // 4 fp32

// RNE float->bf16 (same as __float2bfloat16 modulo NaN, which we don't produce)
__device__ inline unsigned short f2b(float f) {
    unsigned u = __builtin_bit_cast(unsigned, f);
    unsigned r = (u + 0x7fffu + ((u >> 16) & 1u)) >> 16;
    return (unsigned short)r;
}

__device__ inline float sigm(float x) { return 1.f / (1.f + __expf(-x)); }
__device__ inline float tanh_f(float x) {
    float e = __expf(-2.f * fabsf(x));
    float r = (1.f - e) / (1.f + e);
    return copysignf(r, x);
}

__device__ inline void gload_lds16(const void* g, void* l) {
    __builtin_amdgcn_global_load_lds(
        (const __attribute__((address_space(1))) void*)g,
        (__attribute__((address_space(3))) void*)l, 16, 0, 0);
}

// ---------------------------------------------------------------------------
// Prep: [0,256) WhT (2 dirs) + flags zero, [256,2256) Wt = W_out^T bf16,
//       [2256,2768) x_proj TRANSPOSED to [t][gate_col][batch]
// ---------------------------------------------------------------------------
__global__ __launch_bounds__(256, 2) void prep_kernel(
    const int* __restrict__ x, const float* __restrict__ emb,
    const float* __restrict__ Wi_f, const float* __restrict__ Wh_f, const float* __restrict__ b_f,
    const float* __restrict__ Wi_b, const float* __restrict__ Wh_b, const float* __restrict__ b_b,
    const float* __restrict__ W_out,
    float* __restrict__ xp_f, float* __restrict__ xp_b,
    unsigned short* __restrict__ WhT_f, unsigned short* __restrict__ WhT_b,
    unsigned short* __restrict__ Wt,
    unsigned int* __restrict__ flags)
{
    __shared__ float lds[128 * 65];
    __shared__ int xidx[16];
    const int bid = blockIdx.x, tid = threadIdx.x;

    if (bid < 256) {
        // block 0 also zeroes the per-step handshake flags (fresh every launch
        // so hipGraph replays don't see stale counters)
        if (bid == 0) {
            for (int i = tid; i < 2 * T_LEN; i += 256) flags[i] = 0;
        }
        // WhT[n][k] = bf16(Wh[k][n]);  tile: 32 k x 64 n
        const int dir = bid >> 7, b2 = bid & 127;
        const float* Wh = dir ? Wh_b : Wh_f;
        unsigned short* WhT = dir ? WhT_b : WhT_f;
        const int k0 = (b2 >> 4) * 32, n0 = (b2 & 15) * 64;
        for (int it = 0; it < 8; ++it) {
            int idx = it * 256 + tid, kk = idx >> 6, nn = idx & 63;
            lds[kk * 65 + nn] = Wh[(k0 + kk) * G4 + n0 + nn];
        }
        __syncthreads();
        int nn = tid >> 2, kq = (tid & 3) * 8;
        bh8 v;
        #pragma unroll
        for (int j = 0; j < 8; ++j) v[j] = (short)f2b(lds[(kq + j) * 65 + nn]);
        *(bh8*)&WhT[(size_t)(n0 + nn) * HID + k0 + kq] = v;
    } else if (bid < 2256) {
        // Wt[n][k] = bf16(W_out[k][n]);  tile: 128 k x 64 n
        const int b2 = bid - 256;
        const int k0 = (b2 / 500) * 128, n0 = (b2 % 500) * 64;
        for (int it = 0; it < 32; ++it) {
            int idx = it * 256 + tid, kk = idx >> 6, nn = idx & 63;
            lds[kk * 65 + nn] = W_out[(size_t)(k0 + kk) * VOC + n0 + nn];
        }
        __syncthreads();
        const int kq = (tid & 15) * 8;
        #pragma unroll
        for (int g = 0; g < 4; ++g) {
            int nn = (tid >> 4) + g * 16;
            bh8 v;
            #pragma unroll
            for (int j = 0; j < 8; ++j) v[j] = (short)f2b(lds[(kq + j) * 65 + nn]);
            *(bh8*)&Wt[(size_t)(n0 + nn) * KDIM + k0 + kq] = v;
        }
    } else {
        // x_proj[t][g][b] = b[g] + sum_e emb[x[b,t]][e] * Wi[e][g]; 16 (t,b) rows/block
        // TRANSPOSED layout: batch innermost so the LSTM loads one dwordx4 per gate tile.
        const int b2 = bid - 2256;
        const int dir = b2 >> 8, rb = b2 & 255;
        const float* Wi = dir ? Wi_b : Wi_f;
        const float* bias = dir ? b_b : b_f;
        float* xp = dir ? xp_b : xp_f;
        const int f0 = rb * 16;
        if (tid < 16) {
            int f = f0 + tid, t = f >> 3, b = f & 7;
            xidx[tid] = x[b * T_LEN + t];
        }
        __syncthreads();
        {
            int rr = tid >> 4, e4 = (tid & 15) * 4;
            const float* er = emb + (size_t)xidx[rr] * EMBD + e4;
            lds[rr * 64 + e4 + 0] = er[0];
            lds[rr * 64 + e4 + 1] = er[1];
            lds[rr * 64 + e4 + 2] = er[2];
            lds[rr * 64 + e4 + 3] = er[3];
        }
        __syncthreads();
        const int g0 = tid * 4;
        float acc[16][4];
        float b0 = bias[g0], b1 = bias[g0 + 1], b2b = bias[g0 + 2], b3 = bias[g0 + 3];
        #pragma unroll
        for (int rr = 0; rr < 16; ++rr) {
            acc[rr][0] = b0; acc[rr][1] = b1; acc[rr][2] = b2b; acc[rr][3] = b3;
        }
        for (int e = 0; e < 64; ++e) {
            const float* wp = Wi + e * G4 + g0;
            float w0 = wp[0], w1 = wp[1], w2 = wp[2], w3 = wp[3];
            #pragma unroll
            for (int rr = 0; rr < 16; ++rr) {
                float xv = lds[rr * 64 + e];
                acc[rr][0] += xv * w0; acc[rr][1] += xv * w1;
                acc[rr][2] += xv * w2; acc[rr][3] += xv * w3;
            }
        }
        #pragma unroll
        for (int rr = 0; rr < 16; ++rr) {
            const int f = f0 + rr, tt = f >> 3, bb = f & 7;
            float* dst = xp + ((size_t)tt * G4 + g0) * 8 + bb;
            dst[0]  = acc[rr][0];
            dst[8]  = acc[rr][1];
            dst[16] = acc[rr][2];
            dst[24] = acc[rr][3];
        }
    }
}

// ---------------------------------------------------------------------------
// Recurrence: 4 blocks = 2 dirs x 2 halves, 512 threads (8 waves, 2/SIMD).
// Each block owns 128 hidden cols x 4 gates; its Wh slice (256 KB) lives
// PERMANENTLY in registers (bfr[4][8] = 128 VGPRs/lane, budget 256).
// Wave w owns hc [w*16, w*16+16): after MFMA one lane holds f,i,g,o for the
// same (batch,hc) -> fused in-register cell update, one barrier pair/step.
// Halves exchange their 2 KB h-slice per step via agent-scope relaxed atomics
// at the coherent point (bypass per-XCD L2), gated by a per-step flag counter.
// ---------------------------------------------------------------------------
__global__ __launch_bounds__(512, 2) void lstm_kernel(
    const float* __restrict__ xp_f, const float* __restrict__ xp_b,
    const unsigned short* __restrict__ WhT_f, const unsigned short* __restrict__ WhT_b,
    unsigned short* __restrict__ h2,
    unsigned long long* __restrict__ hxchg,  // [dir][step][half][8 b][128 hc] bf16, u64 granule
    unsigned int* __restrict__ flags)        // [dir][step]
{
    const int bid = blockIdx.x;
    const int dir = bid >> 1, half = bid & 1;
    const float* xp = dir ? xp_b : xp_f;
    const unsigned short* WhT = dir ? WhT_b : WhT_f;
    const int tid = threadIdx.x;
    const int w = tid >> 6, lane = tid & 63, quad = lane >> 4, l15 = lane & 15;
    const int hcw = half * 128 + w * 16;     // wave's hc base within the direction

    // double-buffered own-half h (rows=batch 0..7, 128 local hc, +8 pad shorts)
    __shared__ unsigned short hlds[2][8][136];

    // Wh B-fragments, resident for the whole kernel: bfr[gate][k-block]
    bh8 bfr[4][8];
    #pragma unroll
    for (int nt = 0; nt < 4; ++nt)
        #pragma unroll
        for (int kt = 0; kt < 8; ++kt)
            bfr[nt][kt] = *(const bh8*)&WhT[(size_t)(nt * 256 + hcw + l15) * HID + kt * 32 + quad * 8];

    unsigned int* flg = flags + dir * T_LEN;
    unsigned long long* hxd = hxchg + (size_t)dir * T_LEN * 512;

    fx4 c = (fx4){0.f, 0.f, 0.f, 0.f};

    // prefetch x_proj for the first step ([t][g][b] layout: one dwordx4 per gate)
    const int t0 = dir ? (T_LEN - 1) : 0;
    fx4 xpre[4];
    #pragma unroll
    for (int nt = 0; nt < 4; ++nt)
        xpre[nt] = (quad < 2)
            ? *(const fx4*)&xp[((size_t)t0 * G4 + nt * 256 + hcw + l15) * 8 + quad * 4]
            : (fx4){0.f, 0.f, 0.f, 0.f};

    for (int s = 0; s < T_LEN; ++s) {
        const int t = dir ? (T_LEN - 1 - s) : s;
        const int p = s & 1;

        fx4 acc[4];
        #pragma unroll
        for (int nt = 0; nt < 4; ++nt) acc[nt] = xpre[nt];

        // issue next step's x_proj prefetch (off the critical path)
        if (s + 1 < T_LEN) {
            const int tn = dir ? (T_LEN - 2 - s) : (s + 1);
            if (quad < 2) {
                #pragma unroll
                for (int nt = 0; nt < 4; ++nt)
                    xpre[nt] = *(const fx4*)&xp[((size_t)tn * G4 + nt * 256 + hcw + l15) * 8 + quad * 4];
            }
        }

        if (s > 0) {
            // ---- own half of h from LDS (k-blocks kb..kb+3) ----
            const int kb = half * 4;
            bh8 af[4];
            #pragma unroll
            for (int k2 = 0; k2 < 4; ++k2)
                af[k2] = *(const bh8*)&hlds[p][l15 & 7][k2 * 32 + quad * 8];
            #pragma unroll
            for (int k2 = 0; k2 < 4; ++k2)
                #pragma unroll
                for (int nt = 0; nt < 4; ++nt)
                    acc[nt] = __builtin_amdgcn_mfma_f32_16x16x32_bf16(af[k2], bfr[nt][kb + k2], acc[nt], 0, 0, 0);

            // ---- partner half: wait for partner's step s-1 publish ----
            unsigned int it = 0;
            while (__hip_atomic_load(&flg[s - 1], __ATOMIC_RELAXED, __HIP_MEMORY_SCOPE_AGENT) < 2u) {
                __builtin_amdgcn_s_sleep(1);
                if (++it > 100000u) break;   // failsafe: never hang the harness
            }
            asm volatile("" ::: "memory");   // no load may move above the spin

            const unsigned long long* hp = hxd + (size_t)(s - 1) * 512 + (1 - half) * 256;
            const int kbp = (1 - half) * 4;
            union { unsigned long long q[2]; bh8 v; } pa[4];
            #pragma unroll
            for (int k2 = 0; k2 < 4; ++k2) {
                const int base = (l15 & 7) * 32 + k2 * 8 + quad * 2;
                pa[k2].q[0] = __hip_atomic_load((unsigned long long*)&hp[base],
                                                __ATOMIC_RELAXED, __HIP_MEMORY_SCOPE_AGENT);
                pa[k2].q[1] = __hip_atomic_load((unsigned long long*)&hp[base + 1],
                                                __ATOMIC_RELAXED, __HIP_MEMORY_SCOPE_AGENT);
            }
            #pragma unroll
            for (int k2 = 0; k2 < 4; ++k2)
                #pragma unroll
                for (int nt = 0; nt < 4; ++nt)
                    acc[nt] = __builtin_amdgcn_mfma_f32_16x16x32_bf16(pa[k2].v, bfr[nt][kbp + k2], acc[nt], 0, 0, 0);
        }

        // ---- fused cell update, fully in-register (lanes 0-31 = batches 0-7) ----
        // acc[0]=f_raw, acc[1]=i_raw, acc[2]=g_raw, acc[3]=o_raw for (b=quad*4+v, hc=hcw+l15)
        if (quad < 2) {
            s4v hv;
            #pragma unroll
            for (int v = 0; v < 4; ++v) {
                float f = sigm(acc[0][v]);
                float i = sigm(acc[1][v]);
                float g = tanh_f(acc[2][v]);
                float o = sigm(acc[3][v]);
                c[v] = f * c[v] + i * g;
                float h = o * tanh_f(c[v]);
                hv[v] = (short)f2b(h);
            }
            #pragma unroll
            for (int v = 0; v < 4; ++v) {
                hlds[1 - p][quad * 4 + v][w * 16 + l15] = (unsigned short)hv[v];
                h2[((size_t)(quad * 4 + v) * T_LEN + t) * KDIM + dir * HID + hcw + l15]
                    = (unsigned short)hv[v];
            }
        }

        __syncthreads();   // barrier A: hlds[1-p] complete block-wide

        if (s + 1 < T_LEN) {
            // repack own half [b][hc] -> coherent-point u64 stores
            if (tid < 256) {
                unsigned long long vq =
                    *(const unsigned long long*)&hlds[1 - p][tid >> 5][(tid & 31) * 4];
                __hip_atomic_store(&hxd[(size_t)s * 512 + half * 256 + tid], vq,
                                   __ATOMIC_RELAXED, __HIP_MEMORY_SCOPE_AGENT);
            }
            // barrier B: per-thread vmcnt(0) drain before arrival => all 256
            // stores globally visible before tid 0 publishes the flag
            __syncthreads();
            if (tid == 0)
                __hip_atomic_fetch_add(&flg[s], 1u, __ATOMIC_RELAXED, __HIP_MEMORY_SCOPE_AGENT);
        }
    }
}

// ---------------------------------------------------------------------------
// Output GEMM (m97-style): C[4096][32000] = A[4096][512] * Bt[32000][512]^T + b
// 128x128 tile, BK=32, 256 threads (4 waves, 2x2), global_load_lds staging.
// ---------------------------------------------------------------------------
__global__ __launch_bounds__(256, 2) void gemm_kernel(
    const unsigned short* __restrict__ A,   // h2 bf16 [4096][512]
    const unsigned short* __restrict__ Bt,  // Wt bf16 [32000][512]
    const float* __restrict__ b_out,
    float* __restrict__ out)
{
    const int bid = blockIdx.x;
    const int nb = bid % 250, mb = bid / 250;
    const int tid = threadIdx.x;
    const int wv = tid >> 6, lane = tid & 63, quad = lane >> 4, l15 = lane & 15;
    const int mrow0 = (wv >> 1) * 64, ncol0 = (wv & 1) * 64;

    __shared__ unsigned short smA[128 * 32];
    __shared__ unsigned short smB[128 * 32];

    fx4 acc[4][4];
    #pragma unroll
    for (int i = 0; i < 4; ++i)
        #pragma unroll
        for (int j = 0; j < 4; ++j) acc[i][j] = (fx4){0.f, 0.f, 0.f, 0.f};

    for (int kb = 0; kb < 16; ++kb) {
        __syncthreads();
        #pragma unroll
        for (int i = 0; i < 2; ++i) {
            const int f = ((i * 4 + wv) * 64 + lane) * 16;  // byte offset in 8KB tile
            const int r = f >> 6, cb = f & 63;
            const char* ga = (const char*)A + ((size_t)(mb * 128 + r) * KDIM + kb * 32) * 2 + cb;
            gload_lds16(ga, (char*)smA + (i * 4 + wv) * 1024);
            const char* gb = (const char*)Bt + ((size_t)(nb * 128 + r) * KDIM + kb * 32) * 2 + cb;
            gload_lds16(gb, (char*)smB + (i * 4 + wv) * 1024);
        }
        __syncthreads();
        bh8 a[4], b[4];
        #pragma unroll
        for (int mt = 0; mt < 4; ++mt)
            a[mt] = *(const bh8*)&smA[(mrow0 + mt * 16 + l15) * 32 + quad * 8];
        #pragma unroll
        for (int nt = 0; nt < 4; ++nt)
            b[nt] = *(const bh8*)&smB[(ncol0 + nt * 16 + l15) * 32 + quad * 8];
        #pragma unroll
        for (int mt = 0; mt < 4; ++mt)
            #pragma unroll
            for (int nt = 0; nt < 4; ++nt)
                acc[mt][nt] = __builtin_amdgcn_mfma_f32_16x16x32_bf16(a[mt], b[nt], acc[mt][nt], 0, 0, 0);
    }

    float bia[4];
    #pragma unroll
    for (int nt = 0; nt < 4; ++nt)
        bia[nt] = b_out[nb * 128 + ncol0 + nt * 16 + l15];
    #pragma unroll
    for (int mt = 0; mt < 4; ++mt) {
        const int grow0 = mb * 128 + mrow0 + mt * 16 + quad * 4;
        #pragma unroll
        for (int nt = 0; nt < 4; ++nt) {
            const int gcol = nb * 128 + ncol0 + nt * 16 + l15;
            #pragma unroll
            for (int v = 0; v < 4; ++v)
                out[(size_t)(grow0 + v) * VOC + gcol] = acc[mt][nt][v] + bia[nt];
        }
    }
}

// ---------------------------------------------------------------------------
extern "C" void kernel_launch(void* const* d_in, const int* in_sizes, int n_in,
                              void* d_out, int out_size, void* d_ws, size_t ws_size,
                              hipStream_t stream) {
    const int*   x     = (const int*)d_in[0];
    const float* emb   = (const float*)d_in[1];
    const float* Wi_f  = (const float*)d_in[2];
    const float* Wh_f  = (const float*)d_in[3];
    const float* b_f   = (const float*)d_in[4];
    const float* Wi_b  = (const float*)d_in[5];
    const float* Wh_b  = (const float*)d_in[6];
    const float* b_b   = (const float*)d_in[7];
    const float* W_out = (const float*)d_in[8];
    const float* b_out = (const float*)d_in[9];
    float* out = (float*)d_out;

    char* ws = (char*)d_ws;
    float* xp_f           = (float*)(ws);                      // 16,777,216 B ([t][g][b])
    float* xp_b           = (float*)(ws + 16777216);           // 16,777,216 B
    unsigned short* WhT_f = (unsigned short*)(ws + 33554432);  //    524,288 B
    unsigned short* WhT_b = (unsigned short*)(ws + 34078720);  //    524,288 B
    unsigned short* Wt    = (unsigned short*)(ws + 34603008);  // 32,768,000 B
    unsigned short* h2    = (unsigned short*)(ws + 67371008);  //  4,194,304 B
    unsigned long long* hxchg = (unsigned long long*)(ws + 71565312);  // 4,194,304 B
    unsigned int* flags   = (unsigned int*)(ws + 75759616);    //      4,096 B  (~75.8 MB total)

    prep_kernel<<<2768, 256, 0, stream>>>(x, emb, Wi_f, Wh_f, b_f, Wi_b, Wh_b, b_b,
                                          W_out, xp_f, xp_b, WhT_f, WhT_b, Wt, flags);
    lstm_kernel<<<4, 512, 0, stream>>>(xp_f, xp_b, WhT_f, WhT_b, h2, hxchg, flags);
    gemm_kernel<<<8000, 256, 0, stream>>>(h2, Wt, b_out, out);
}

// Round 3
// 5492.949 us; speedup vs baseline: 1.1405x; 1.1405x over previous
//
#include <hip/hip_runtime.h>
#include <hip/hip_bf16.h>

#define T_LEN 512
#define BATCH 8
#define HID   256
#define G4    1024   // 4H
#define EMBD  64
#define VOC   32000
#define KDIM  512    // 2H

typedef __attribute__((ext_vector_type(8))) short bh8;    // 8 bf16 (4 VGPRs)
typedef __attribute__((ext_vector_type(4))) short s4v;    // 4 bf16 (8 B)
typedef __attribute__((ext_vector_type(4))) float fx4;    // 4 fp32

// RNE float->bf16 (same as __float2bfloat16 modulo NaN, which we don't produce)
__device__ inline unsigned short f2b(float f) {
    unsigned u = __builtin_bit_cast(unsigned, f);
    unsigned r = (u + 0x7fffu + ((u >> 16) & 1u)) >> 16;
    return (unsigned short)r;
}

__device__ inline float sigm(float x) { return 1.f / (1.f + __expf(-x)); }
__device__ inline float tanh_f(float x) {
    float e = __expf(-2.f * fabsf(x));
    float r = (1.f - e) / (1.f + e);
    return copysignf(r, x);
}

__device__ inline void gload_lds16(const void* g, void* l) {
    __builtin_amdgcn_global_load_lds(
        (const __attribute__((address_space(1))) void*)g,
        (__attribute__((address_space(3))) void*)l, 16, 0, 0);
}

// ---------------------------------------------------------------------------
// Prep: [0,256) WhT (2 dirs), [256,2256) Wt = W_out^T bf16,
//       [2256,2768) x_proj TRANSPOSED to [t][gate_col][batch]
// ---------------------------------------------------------------------------
__global__ __launch_bounds__(256, 2) void prep_kernel(
    const int* __restrict__ x, const float* __restrict__ emb,
    const float* __restrict__ Wi_f, const float* __restrict__ Wh_f, const float* __restrict__ b_f,
    const float* __restrict__ Wi_b, const float* __restrict__ Wh_b, const float* __restrict__ b_b,
    const float* __restrict__ W_out,
    float* __restrict__ xp_f, float* __restrict__ xp_b,
    unsigned short* __restrict__ WhT_f, unsigned short* __restrict__ WhT_b,
    unsigned short* __restrict__ Wt)
{
    __shared__ float lds[128 * 65];
    __shared__ int xidx[16];
    const int bid = blockIdx.x, tid = threadIdx.x;

    if (bid < 256) {
        // WhT[n][k] = bf16(Wh[k][n]);  tile: 32 k x 64 n
        const int dir = bid >> 7, b2 = bid & 127;
        const float* Wh = dir ? Wh_b : Wh_f;
        unsigned short* WhT = dir ? WhT_b : WhT_f;
        const int k0 = (b2 >> 4) * 32, n0 = (b2 & 15) * 64;
        for (int it = 0; it < 8; ++it) {
            int idx = it * 256 + tid, kk = idx >> 6, nn = idx & 63;
            lds[kk * 65 + nn] = Wh[(k0 + kk) * G4 + n0 + nn];
        }
        __syncthreads();
        int nn = tid >> 2, kq = (tid & 3) * 8;
        bh8 v;
        #pragma unroll
        for (int j = 0; j < 8; ++j) v[j] = (short)f2b(lds[(kq + j) * 65 + nn]);
        *(bh8*)&WhT[(size_t)(n0 + nn) * HID + k0 + kq] = v;
    } else if (bid < 2256) {
        // Wt[n][k] = bf16(W_out[k][n]);  tile: 128 k x 64 n
        const int b2 = bid - 256;
        const int k0 = (b2 / 500) * 128, n0 = (b2 % 500) * 64;
        for (int it = 0; it < 32; ++it) {
            int idx = it * 256 + tid, kk = idx >> 6, nn = idx & 63;
            lds[kk * 65 + nn] = W_out[(size_t)(k0 + kk) * VOC + n0 + nn];
        }
        __syncthreads();
        const int kq = (tid & 15) * 8;
        #pragma unroll
        for (int g = 0; g < 4; ++g) {
            int nn = (tid >> 4) + g * 16;
            bh8 v;
            #pragma unroll
            for (int j = 0; j < 8; ++j) v[j] = (short)f2b(lds[(kq + j) * 65 + nn]);
            *(bh8*)&Wt[(size_t)(n0 + nn) * KDIM + k0 + kq] = v;
        }
    } else {
        // x_proj[t][g][b] = b[g] + sum_e emb[x[b,t]][e] * Wi[e][g]; 16 (t,b) rows/block
        // TRANSPOSED layout: batch innermost so the LSTM loads one dwordx4 per gate tile.
        const int b2 = bid - 2256;
        const int dir = b2 >> 8, rb = b2 & 255;
        const float* Wi = dir ? Wi_b : Wi_f;
        const float* bias = dir ? b_b : b_f;
        float* xp = dir ? xp_b : xp_f;
        const int f0 = rb * 16;
        if (tid < 16) {
            int f = f0 + tid, t = f >> 3, b = f & 7;
            xidx[tid] = x[b * T_LEN + t];
        }
        __syncthreads();
        {
            int rr = tid >> 4, e4 = (tid & 15) * 4;
            const float* er = emb + (size_t)xidx[rr] * EMBD + e4;
            lds[rr * 64 + e4 + 0] = er[0];
            lds[rr * 64 + e4 + 1] = er[1];
            lds[rr * 64 + e4 + 2] = er[2];
            lds[rr * 64 + e4 + 3] = er[3];
        }
        __syncthreads();
        const int g0 = tid * 4;
        float acc[16][4];
        float b0 = bias[g0], b1 = bias[g0 + 1], b2b = bias[g0 + 2], b3 = bias[g0 + 3];
        #pragma unroll
        for (int rr = 0; rr < 16; ++rr) {
            acc[rr][0] = b0; acc[rr][1] = b1; acc[rr][2] = b2b; acc[rr][3] = b3;
        }
        for (int e = 0; e < 64; ++e) {
            const float* wp = Wi + e * G4 + g0;
            float w0 = wp[0], w1 = wp[1], w2 = wp[2], w3 = wp[3];
            #pragma unroll
            for (int rr = 0; rr < 16; ++rr) {
                float xv = lds[rr * 64 + e];
                acc[rr][0] += xv * w0; acc[rr][1] += xv * w1;
                acc[rr][2] += xv * w2; acc[rr][3] += xv * w3;
            }
        }
        #pragma unroll
        for (int rr = 0; rr < 16; ++rr) {
            const int f = f0 + rr, tt = f >> 3, bb = f & 7;
            float* dst = xp + ((size_t)tt * G4 + g0) * 8 + bb;
            dst[0]  = acc[rr][0];
            dst[8]  = acc[rr][1];
            dst[16] = acc[rr][2];
            dst[24] = acc[rr][3];
        }
    }
}

// ---------------------------------------------------------------------------
// Recurrence: ONE block per direction (grid=2), 1024 threads = 16 waves
// (4 waves/SIMD -> VGPR budget 512/wave; we need ~230).
// Wave w owns hc [w*16, w*16+16) for ALL 4 gates: bfr[4][8] = 128 VGPRs of
// Wh B-fragments, loaded once and PINNED into registers with an empty
// "+v" inline asm (defeats the round-0 failure where the compiler kept the
// loads inside the loop and re-streamed 512 KB/step from L2).
// All indices into bfr are compile-time constants (rule #20).
// After the MFMA one lane holds f,i,g,o raw gates for the same (batch,hc)
// -> fused in-register cell update, h broadcast via LDS double-buffer,
// ONE __syncthreads per step. No cross-block communication of any kind.
// ---------------------------------------------------------------------------
__global__ __launch_bounds__(1024, 1) void lstm_kernel(
    const float* __restrict__ xp_f, const float* __restrict__ xp_b,
    const unsigned short* __restrict__ WhT_f, const unsigned short* __restrict__ WhT_b,
    unsigned short* __restrict__ h2)
{
    const int dir = blockIdx.x;
    const float* xp = dir ? xp_b : xp_f;
    const unsigned short* WhT = dir ? WhT_b : WhT_f;
    const int tid = threadIdx.x;
    const int w = tid >> 6, lane = tid & 63, quad = lane >> 4, l15 = lane & 15;
    const int hcw = w * 16;                  // wave's hc base (16 waves x 16 hc = 256)

    // double-buffered h (rows = batch 0..7, 256 hc, +8 pad shorts per row)
    __shared__ unsigned short hlds[2][8][264];

    // Wh B-fragments, resident for the whole kernel.
    // bfr[g][kt] = B[k = kt*32 + quad*8 + j][n = g*256 + hcw + l15]
    bh8 bfr[4][8];
    #pragma unroll
    for (int g = 0; g < 4; ++g)
        #pragma unroll
        for (int kt = 0; kt < 8; ++kt)
            bfr[g][kt] = *(const bh8*)&WhT[(size_t)(g * 256 + hcw + l15) * HID
                                            + kt * 32 + quad * 8];
    // PIN: redefine each fragment through an empty asm so the loop's uses
    // cannot be satisfied by sinking/re-issuing the loads. Values must live
    // in VGPRs across the whole time loop (~230 live regs < 512 budget).
    #pragma unroll
    for (int g = 0; g < 4; ++g)
        #pragma unroll
        for (int kt = 0; kt < 8; ++kt)
            asm volatile("" : "+v"(bfr[g][kt]));

    fx4 c = (fx4){0.f, 0.f, 0.f, 0.f};

    // prefetch x_proj for the first step ([t][g][b] layout: one dwordx4 per gate)
    const int t0 = dir ? (T_LEN - 1) : 0;
    fx4 xpre[4];
    #pragma unroll
    for (int g = 0; g < 4; ++g)
        xpre[g] = (quad < 2)
            ? *(const fx4*)&xp[((size_t)t0 * G4 + g * 256 + hcw + l15) * 8 + quad * 4]
            : (fx4){0.f, 0.f, 0.f, 0.f};

    for (int s = 0; s < T_LEN; ++s) {
        const int t = dir ? (T_LEN - 1 - s) : s;
        const int p = s & 1;

        fx4 acc[4];
        #pragma unroll
        for (int g = 0; g < 4; ++g) acc[g] = xpre[g];

        // issue next step's x_proj prefetch (off the critical path)
        if (s + 1 < T_LEN) {
            const int tn = dir ? (T_LEN - 2 - s) : (s + 1);
            if (quad < 2) {
                #pragma unroll
                for (int g = 0; g < 4; ++g)
                    xpre[g] = *(const fx4*)&xp[((size_t)tn * G4 + g * 256 + hcw + l15) * 8 + quad * 4];
            }
        }

        if (s > 0) {
            // A-fragments of h_prev: A[m = l15][k = kt*32 + quad*8 + j]
            // (rows 8..15 of the MFMA M-dim alias rows 0..7 via l15&7; their
            //  C rows are never read, so aliasing is harmless)
            bh8 af[8];
            #pragma unroll
            for (int kt = 0; kt < 8; ++kt)
                af[kt] = *(const bh8*)&hlds[p][l15 & 7][kt * 32 + quad * 8];
            // gates = x_proj + h_prev @ Wh   (k ascending, same order as the
            // round-0/1 kernels that passed the absmax check)
            #pragma unroll
            for (int kt = 0; kt < 8; ++kt)
                #pragma unroll
                for (int g = 0; g < 4; ++g)
                    acc[g] = __builtin_amdgcn_mfma_f32_16x16x32_bf16(af[kt], bfr[g][kt], acc[g], 0, 0, 0);
        }

        // ---- fused cell update, fully in-register (lanes 0-31 = batches 0-7) ----
        // acc[0]=f_raw, acc[1]=i_raw, acc[2]=g_raw, acc[3]=o_raw
        // for (b = quad*4 + v, hc = hcw + l15)
        if (quad < 2) {
            s4v hv;
            #pragma unroll
            for (int v = 0; v < 4; ++v) {
                float f = sigm(acc[0][v]);
                float i = sigm(acc[1][v]);
                float g = tanh_f(acc[2][v]);
                float o = sigm(acc[3][v]);
                c[v] = f * c[v] + i * g;
                float h = o * tanh_f(c[v]);
                hv[v] = (short)f2b(h);
            }
            #pragma unroll
            for (int v = 0; v < 4; ++v) {
                hlds[1 - p][quad * 4 + v][hcw + l15] = (unsigned short)hv[v];
                h2[((size_t)(quad * 4 + v) * T_LEN + t) * KDIM + dir * HID + hcw + l15]
                    = (unsigned short)hv[v];
            }
        }

        __syncthreads();   // hlds buffer publish/swap (the only per-step barrier)
    }
}

// ---------------------------------------------------------------------------
// Output GEMM (m97-style): C[4096][32000] = A[4096][512] * Bt[32000][512]^T + b
// 128x128 tile, BK=32, 256 threads (4 waves, 2x2), global_load_lds staging.
// ---------------------------------------------------------------------------
__global__ __launch_bounds__(256, 2) void gemm_kernel(
    const unsigned short* __restrict__ A,   // h2 bf16 [4096][512]
    const unsigned short* __restrict__ Bt,  // Wt bf16 [32000][512]
    const float* __restrict__ b_out,
    float* __restrict__ out)
{
    const int bid = blockIdx.x;
    const int nb = bid % 250, mb = bid / 250;
    const int tid = threadIdx.x;
    const int wv = tid >> 6, lane = tid & 63, quad = lane >> 4, l15 = lane & 15;
    const int mrow0 = (wv >> 1) * 64, ncol0 = (wv & 1) * 64;

    __shared__ unsigned short smA[128 * 32];
    __shared__ unsigned short smB[128 * 32];

    fx4 acc[4][4];
    #pragma unroll
    for (int i = 0; i < 4; ++i)
        #pragma unroll
        for (int j = 0; j < 4; ++j) acc[i][j] = (fx4){0.f, 0.f, 0.f, 0.f};

    for (int kb = 0; kb < 16; ++kb) {
        __syncthreads();
        #pragma unroll
        for (int i = 0; i < 2; ++i) {
            const int f = ((i * 4 + wv) * 64 + lane) * 16;  // byte offset in 8KB tile
            const int r = f >> 6, cb = f & 63;
            const char* ga = (const char*)A + ((size_t)(mb * 128 + r) * KDIM + kb * 32) * 2 + cb;
            gload_lds16(ga, (char*)smA + (i * 4 + wv) * 1024);
            const char* gb = (const char*)Bt + ((size_t)(nb * 128 + r) * KDIM + kb * 32) * 2 + cb;
            gload_lds16(gb, (char*)smB + (i * 4 + wv) * 1024);
        }
        __syncthreads();
        bh8 a[4], b[4];
        #pragma unroll
        for (int mt = 0; mt < 4; ++mt)
            a[mt] = *(const bh8*)&smA[(mrow0 + mt * 16 + l15) * 32 + quad * 8];
        #pragma unroll
        for (int nt = 0; nt < 4; ++nt)
            b[nt] = *(const bh8*)&smB[(ncol0 + nt * 16 + l15) * 32 + quad * 8];
        #pragma unroll
        for (int mt = 0; mt < 4; ++mt)
            #pragma unroll
            for (int nt = 0; nt < 4; ++nt)
                acc[mt][nt] = __builtin_amdgcn_mfma_f32_16x16x32_bf16(a[mt], b[nt], acc[mt][nt], 0, 0, 0);
    }

    float bia[4];
    #pragma unroll
    for (int nt = 0; nt < 4; ++nt)
        bia[nt] = b_out[nb * 128 + ncol0 + nt * 16 + l15];
    #pragma unroll
    for (int mt = 0; mt < 4; ++mt) {
        const int grow0 = mb * 128 + mrow0 + mt * 16 + quad * 4;
        #pragma unroll
        for (int nt = 0; nt < 4; ++nt) {
            const int gcol = nb * 128 + ncol0 + nt * 16 + l15;
            #pragma unroll
            for (int v = 0; v < 4; ++v)
                out[(size_t)(grow0 + v) * VOC + gcol] = acc[mt][nt][v] + bia[nt];
        }
    }
}

// ---------------------------------------------------------------------------
extern "C" void kernel_launch(void* const* d_in, const int* in_sizes, int n_in,
                              void* d_out, int out_size, void* d_ws, size_t ws_size,
                              hipStream_t stream) {
    const int*   x     = (const int*)d_in[0];
    const float* emb   = (const float*)d_in[1];
    const float* Wi_f  = (const float*)d_in[2];
    const float* Wh_f  = (const float*)d_in[3];
    const float* b_f   = (const float*)d_in[4];
    const float* Wi_b  = (const float*)d_in[5];
    const float* Wh_b  = (const float*)d_in[6];
    const float* b_b   = (const float*)d_in[7];
    const float* W_out = (const float*)d_in[8];
    const float* b_out = (const float*)d_in[9];
    float* out = (float*)d_out;

    char* ws = (char*)d_ws;
    float* xp_f           = (float*)(ws);                      // 16,777,216 B ([t][g][b])
    float* xp_b           = (float*)(ws + 16777216);           // 16,777,216 B
    unsigned short* WhT_f = (unsigned short*)(ws + 33554432);  //    524,288 B
    unsigned short* WhT_b = (unsigned short*)(ws + 34078720);  //    524,288 B
    unsigned short* Wt    = (unsigned short*)(ws + 34603008);  // 32,768,000 B
    unsigned short* h2    = (unsigned short*)(ws + 67371008);  //  4,194,304 B  (~71.6 MB total)

    prep_kernel<<<2768, 256, 0, stream>>>(x, emb, Wi_f, Wh_f, b_f, Wi_b, Wh_b, b_b,
                                          W_out, xp_f, xp_b, WhT_f, WhT_b, Wt);
    lstm_kernel<<<2, 1024, 0, stream>>>(xp_f, xp_b, WhT_f, WhT_b, h2);
    gemm_kernel<<<8000, 256, 0, stream>>>(h2, Wt, b_out, out);
}